// Round 4
// baseline (151.838 us; speedup 1.0000x reference)
//
#include <hip/hip_runtime.h>
#include <hip/hip_bf16.h>

// Problem constants: B=16, L=50, D=8, H=128, E=128, NC=1000, NI=8192
#define NB 16
#define NL 50
#define ND 8
#define NH 128
#define NC 1000
#define NI 8192

// Output flat offsets (return order)
#define OFF_CAT  0
#define OFF_DS   128000
#define OFF_DSC  134400
#define OFF_EMB  1182976
#define OFF_EMBC 1285376
#define OFF_LOSS 2333952

// Workspace layout (floats)
#define WS_SPART 0          // 128*5*128 = 81920  (sum-exp partials per l-chunk)
#define WS_PK    81920      // 800*128   = 102400
#define WS_PKCT  184320     // 128*8192  = 1048576 (transposed [h][i])
#define WS_WP    1232896    // 128*128   = 16384  (W' = Wk @ Wk1)
#define WS_BP    1249280    // 128               (b' = bk @ Wk1)
// total = 1249408 floats ~= 5.0 MB

// ---------------------------------------------------------------------------
// K0: prep. blocks 0..63: W'[2r..2r+1][:] = Wk[2r..2r+1][:] @ Wk1.
// block 64: b' = bk @ Wk1, and zero the loss accumulator.
__global__ __launch_bounds__(128) void k_prep(
    const float* __restrict__ Wk, const float* __restrict__ bk,
    const float* __restrict__ W1, float* __restrict__ ws_wp,
    float* __restrict__ ws_bp, float* __restrict__ out_loss)
{
    const int t = threadIdx.x;
    const int bxx = blockIdx.x;
    __shared__ float wk_s[256];
    const float* __restrict__ Wk1 = W1 + 128 * 128;
    if (bxx < 64) {
        const int r0 = bxx * 2;
        wk_s[t]       = Wk[r0 * 128 + t];
        wk_s[128 + t] = Wk[(r0 + 1) * 128 + t];
        __syncthreads();
        float a0 = 0.f, a1 = 0.f;
        for (int k = 0; k < 128; k += 4) {
            #pragma unroll
            for (int j = 0; j < 4; ++j) {
                const float w = Wk1[(k + j) * 128 + t];
                a0 = fmaf(wk_s[k + j], w, a0);
                a1 = fmaf(wk_s[128 + k + j], w, a1);
            }
        }
        ws_wp[r0 * 128 + t]       = a0;
        ws_wp[(r0 + 1) * 128 + t] = a1;
    } else {
        wk_s[t] = bk[t];
        __syncthreads();
        float a0 = 0.f;
        for (int k = 0; k < 128; k += 4) {
            #pragma unroll
            for (int j = 0; j < 4; ++j)
                a0 = fmaf(wk_s[k + j], Wk1[(k + j) * 128 + t], a0);
        }
        ws_bp[t] = a0;
        if (t == 0) out_loss[0] = 0.f;
    }
}

// ---------------------------------------------------------------------------
// K1 (one launch, 256 thr): blocks 0..99 session (8 rows: emb out + pk),
// 100..611 candidates (16 rows: emb_cand out + pkcT), 612..1251 dsum partials.
// All roles read only global inputs + K0 outputs -> fully parallel.
__global__ __launch_bounds__(256) void k_main(
    const int* __restrict__ inp, const int* __restrict__ cand,
    const float* __restrict__ emb_table, const float* __restrict__ Wd,
    const float* __restrict__ ws_wp, const float* __restrict__ ws_bp,
    float* __restrict__ out_emb, float* __restrict__ out_embc,
    float* __restrict__ ws_pk, float* __restrict__ ws_pkcT,
    float* __restrict__ ws_spart)
{
    const int bx = blockIdx.x;
    const int t = threadIdx.x;
    const int c = t & 127, g = t >> 7;
    __shared__ __align__(16) float smem[2176];

    if (bx < 100) {
        // ---- session: 8 rows; pk = emb @ W' + b' ----
        const int r0 = bx * 8;
        float* e_s = smem;                       // 1024
        #pragma unroll
        for (int r = 0; r < 4; ++r) {
            const int gr = g * 4 + r;
            const int cat = inp[r0 + gr];
            const float v = emb_table[cat * 128 + c];
            e_s[gr * 128 + c] = v;
            out_emb[(r0 + gr) * 128 + c] = v;
        }
        __syncthreads();
        const float bpv = ws_bp[c];
        float acc[4] = {bpv, bpv, bpv, bpv};
        for (int k = 0; k < 128; k += 4) {
            const float w0 = ws_wp[(k + 0) * 128 + c], w1 = ws_wp[(k + 1) * 128 + c];
            const float w2 = ws_wp[(k + 2) * 128 + c], w3 = ws_wp[(k + 3) * 128 + c];
            #pragma unroll
            for (int r = 0; r < 4; ++r) {
                const float4 e4 = *reinterpret_cast<const float4*>(&e_s[(g * 4 + r) * 128 + k]);
                acc[r] = fmaf(e4.w, w3, fmaf(e4.z, w2, fmaf(e4.y, w1, fmaf(e4.x, w0, acc[r]))));
            }
        }
        #pragma unroll
        for (int r = 0; r < 4; ++r) ws_pk[(r0 + g * 4 + r) * 128 + c] = acc[r];
    } else if (bx < 612) {
        // ---- candidates: 16 rows; pkc = emb_cand @ W' + b', stored [h][i] ----
        const int i0 = (bx - 100) * 16;
        float* e_s = smem;                       // 2048
        #pragma unroll
        for (int r = 0; r < 8; ++r) {
            const int gr = g * 8 + r;
            const int cat = cand[i0 + gr];
            const float v = emb_table[cat * 128 + c];
            e_s[gr * 128 + c] = v;
            out_embc[(i0 + gr) * 128 + c] = v;
        }
        __syncthreads();
        const float bpv = ws_bp[c];
        float acc[8];
        #pragma unroll
        for (int r = 0; r < 8; ++r) acc[r] = bpv;
        for (int k = 0; k < 128; k += 4) {
            const float w0 = ws_wp[(k + 0) * 128 + c], w1 = ws_wp[(k + 1) * 128 + c];
            const float w2 = ws_wp[(k + 2) * 128 + c], w3 = ws_wp[(k + 3) * 128 + c];
            #pragma unroll
            for (int r = 0; r < 8; ++r) {
                const float4 e4 = *reinterpret_cast<const float4*>(&e_s[(g * 8 + r) * 128 + k]);
                acc[r] = fmaf(e4.w, w3, fmaf(e4.z, w2, fmaf(e4.y, w1, fmaf(e4.x, w0, acc[r]))));
            }
        }
        // LDS transpose (stride 132) then 64B-contiguous stores
        __syncthreads();
        float* tb = smem;                        // 16*132 = 2112
        #pragma unroll
        for (int r = 0; r < 8; ++r) tb[(g * 8 + r) * 132 + c] = acc[r];
        __syncthreads();
        #pragma unroll
        for (int p = 0; p < 2; ++p) {
            const int h = p * 64 + (t >> 2);
            const int ib = (t & 3) * 4;
            const float4 v = make_float4(tb[(ib + 0) * 132 + h], tb[(ib + 1) * 132 + h],
                                         tb[(ib + 2) * 132 + h], tb[(ib + 3) * 132 + h]);
            *reinterpret_cast<float4*>(&ws_pkcT[(size_t)h * NI + i0 + ib]) = v;
        }
    } else {
        // ---- dsum partial: Spart[bd][chunk][h] over 10 l's; gathers emb itself ----
        const int idx = bx - 612;
        const int bd = idx / 5, chunk = idx % 5;
        const int b = bd >> 3, d = bd & 7;
        const int half = g;
        float* se = smem;                        // 1280
        float* ss = smem + 1280;                 // 256
        for (int ii = t; ii < 1280; ii += 256) {
            const int row = ii >> 7, col = ii & 127;
            const int cat = inp[b * NL + chunk * 10 + row];
            se[ii] = emb_table[cat * 128 + col];
        }
        __syncthreads();
        const float* __restrict__ wp = Wd + d * 128 + c;
        float acc[5] = {0.f, 0.f, 0.f, 0.f, 0.f};
        const int l0 = half * 5;
        for (int k = 0; k < 128; k += 4) {
            const float w0 = wp[(k + 0) * 1024], w1 = wp[(k + 1) * 1024];
            const float w2 = wp[(k + 2) * 1024], w3 = wp[(k + 3) * 1024];
            #pragma unroll
            for (int li = 0; li < 5; ++li) {
                const float4 e4 = *reinterpret_cast<const float4*>(&se[(l0 + li) * 128 + k]);
                acc[li] = fmaf(e4.w, w3, fmaf(e4.z, w2, fmaf(e4.y, w1, fmaf(e4.x, w0, acc[li]))));
            }
        }
        float s = 0.f;
        #pragma unroll
        for (int li = 0; li < 5; ++li) s += expf(acc[li]);
        ss[half * 128 + c] = s;
        __syncthreads();
        if (half == 0)
            ws_spart[(bd * 5 + chunk) * 128 + c] = ss[c] + ss[128 + c];
    }
}

// ---------------------------------------------------------------------------
// K2 (one launch, 256 thr): blocks 0..511 cand_score (recompute agg+pd2 from
// spart), 512..639 catgy (recompute agg), 640..655 per-b loss + demand_score.
__global__ __launch_bounds__(256) void k_tail(
    const float* __restrict__ ws_spart, const float* __restrict__ ws_pk,
    const float* __restrict__ ws_pkcT, const float* __restrict__ W1,
    const float* __restrict__ b1, const float* __restrict__ w_score,
    const float* __restrict__ Wc, const float* __restrict__ bc,
    float* __restrict__ out_cat, float* __restrict__ out_ds,
    float* __restrict__ out_dsc, float* __restrict__ out_loss)
{
    const int bx = blockIdx.x;
    const int t = threadIdx.x;
    __shared__ __align__(16) float smem[5408];
    float* a_s  = smem;            // 1024
    float* pd_s = smem + 1024;     // 1024
    float* ws_s = smem + 2048;     // 128
    float* pk_s = smem + 2176;     // 3200 (also reused as sp[] in loss)
    float* aux  = smem + 5376;     // normp[16] + wred[4]

    if (bx < 512) {
        // ================= cand_score =================
        const int b = bx >> 5;
        const int r0 = b * 8;
        const int i = (bx & 31) * 256 + t;
        // agg recompute
        for (int j = t; j < 1024; j += 256) {
            const int row = j >> 7, cc = j & 127;
            float s = 0.f;
            #pragma unroll
            for (int ch = 0; ch < 5; ++ch) s += ws_spart[((r0 + row) * 5 + ch) * 128 + cc];
            a_s[j] = logf(s);
        }
        if (t < 128) ws_s[t] = w_score[t];
        __syncthreads();
        // pd2 = agg @ Wd1 + b1
        {
            const int c = t & 127, g = t >> 7;
            const float b1v = b1[c];
            float acc[4] = {b1v, b1v, b1v, b1v};
            for (int k = 0; k < 128; ++k) {
                const float w1v = W1[k * 128 + c];
                #pragma unroll
                for (int r = 0; r < 4; ++r)
                    acc[r] = fmaf(a_s[(g * 4 + r) * 128 + k], w1v, acc[r]);
            }
            #pragma unroll
            for (int r = 0; r < 4; ++r) pd_s[(g * 4 + r) * 128 + c] = acc[r];
        }
        __syncthreads();
        // scoring
        float acc[8];
        #pragma unroll
        for (int r = 0; r < 8; ++r) acc[r] = 0.f;
        for (int h = 0; h < 128; h += 4) {
            const float pv0 = ws_pkcT[(size_t)(h + 0) * NI + i];
            const float pv1 = ws_pkcT[(size_t)(h + 1) * NI + i];
            const float pv2 = ws_pkcT[(size_t)(h + 2) * NI + i];
            const float pv3 = ws_pkcT[(size_t)(h + 3) * NI + i];
            const float4 w4 = *reinterpret_cast<const float4*>(&ws_s[h]);
            #pragma unroll
            for (int r = 0; r < 8; ++r) {
                const float4 p4 = *reinterpret_cast<const float4*>(&pd_s[r * 128 + h]);
                acc[r] = fmaf(fmaxf(p4.x + pv0, 0.f), w4.x, acc[r]);
                acc[r] = fmaf(fmaxf(p4.y + pv1, 0.f), w4.y, acc[r]);
                acc[r] = fmaf(fmaxf(p4.z + pv2, 0.f), w4.z, acc[r]);
                acc[r] = fmaf(fmaxf(p4.w + pv3, 0.f), w4.w, acc[r]);
            }
        }
        #pragma unroll
        for (int r = 0; r < 8; ++r) out_dsc[(size_t)(r0 + r) * NI + i] = acc[r];
    } else if (bx < 640) {
        // ================= catgy =================
        const int bd = bx - 512;
        const int c = t & 127, half = t >> 7;
        if (half == 0) {
            float s = 0.f;
            #pragma unroll
            for (int ch = 0; ch < 5; ++ch) s += ws_spart[(bd * 5 + ch) * 128 + c];
            a_s[c] = logf(s);
        }
        __syncthreads();
        float acc4[4];
        int   col4[4];
        #pragma unroll
        for (int j = 0; j < 4; ++j) {
            const int col = t + j * 256;
            col4[j] = (col < NC) ? col : (NC - 1);
            acc4[j] = bc[col4[j]];
        }
        for (int k = 0; k < 128; ++k) {
            const float av = a_s[k];
            const float* wr = Wc + (size_t)k * NC;
            #pragma unroll
            for (int j = 0; j < 4; ++j) acc4[j] = fmaf(av, wr[col4[j]], acc4[j]);
        }
        #pragma unroll
        for (int j = 0; j < 4; ++j) {
            const int col = t + j * 256;
            if (col < NC) out_cat[bd * NC + col] = acc4[j];
        }
    } else {
        // ================= per-b loss + demand_score =================
        const int b = bx - 640;
        const int c = t & 127, g = t >> 7;
        const int w = t >> 6, lane = t & 63;
        float* normp = aux;            // [4][4]
        float* wred  = aux + 16;       // [4]
        float* sp    = pk_s;           // [2][128] (pk_s free during loss)
        // agg recompute (8 rows)
        for (int j = t; j < 1024; j += 256) {
            const int row = j >> 7, cc = j & 127;
            float s = 0.f;
            #pragma unroll
            for (int ch = 0; ch < 5; ++ch) s += ws_spart[((b * 8 + row) * 5 + ch) * 128 + cc];
            a_s[j] = logf(s);
        }
        if (t < 128) ws_s[t] = w_score[t];
        __syncthreads();
        // ---- loss ----
        float a[4];
        #pragma unroll
        for (int r = 0; r < 4; ++r) a[r] = a_s[(g * 4 + r) * 128 + c];
        #pragma unroll
        for (int r = 0; r < 4; ++r) {
            float s = a[r] * a[r];
            s += __shfl_down(s, 32); s += __shfl_down(s, 16); s += __shfl_down(s, 8);
            s += __shfl_down(s, 4);  s += __shfl_down(s, 2);  s += __shfl_down(s, 1);
            if (lane == 0) normp[w * 4 + r] = s;
        }
        __syncthreads();
        float Sp = 0.f;
        #pragma unroll
        for (int r = 0; r < 4; ++r) {
            const float nsq = normp[(2 * g) * 4 + r] + normp[(2 * g + 1) * 4 + r];
            const float iv = 1.f / (sqrtf(nsq) + 1e-12f);
            Sp = fmaf(a[r], iv, Sp);
        }
        sp[g * 128 + c] = Sp;
        __syncthreads();
        float p = 0.f;
        if (t < 128) {
            const float S = sp[c] + sp[128 + c];
            p = S * S;
        }
        p += __shfl_down(p, 32); p += __shfl_down(p, 16); p += __shfl_down(p, 8);
        p += __shfl_down(p, 4);  p += __shfl_down(p, 2);  p += __shfl_down(p, 1);
        if (lane == 0) wred[w] = p;
        __syncthreads();
        if (t == 0) {
            float corr = 0.f;
            #pragma unroll
            for (int d = 0; d < 8; ++d) {
                const float nsq = normp[(2 * (d >> 2)) * 4 + (d & 3)] +
                                  normp[(2 * (d >> 2) + 1) * 4 + (d & 3)];
                const float iv = 1.f / (sqrtf(nsq) + 1e-12f);
                corr = fmaf(nsq, iv * iv, corr);
            }
            atomicAdd(out_loss,
                      (wred[0] + wred[1] + wred[2] + wred[3] - corr) * (1.0f / 896.0f));
        }
        // ---- pd2 = agg @ Wd1 + b1 ----
        {
            const float b1v = b1[c];
            float acc[4] = {b1v, b1v, b1v, b1v};
            for (int k = 0; k < 128; ++k) {
                const float w1v = W1[k * 128 + c];
                #pragma unroll
                for (int r = 0; r < 4; ++r)
                    acc[r] = fmaf(a_s[(g * 4 + r) * 128 + k], w1v, acc[r]);
            }
            #pragma unroll
            for (int r = 0; r < 4; ++r) pd_s[(g * 4 + r) * 128 + c] = acc[r];
        }
        __syncthreads();
        // ---- demand_score: 2 chunks of 25 l's, pk staged in LDS ----
        #pragma unroll
        for (int ch2 = 0; ch2 < 2; ++ch2) {
            const int l0 = ch2 * 25;
            __syncthreads();                      // protect pk_s reuse
            for (int ii = t; ii < 3200; ii += 256)
                pk_s[ii] = ws_pk[(size_t)(b * NL + l0) * 128 + ii];
            __syncthreads();
            for (int pp = w; pp < 200; pp += 4) {
                const int l = pp >> 3, d = pp & 7;
                float v = fmaxf(pd_s[d * 128 + lane] + pk_s[l * 128 + lane], 0.f) * ws_s[lane]
                        + fmaxf(pd_s[d * 128 + 64 + lane] + pk_s[l * 128 + 64 + lane], 0.f) * ws_s[64 + lane];
                v += __shfl_down(v, 32); v += __shfl_down(v, 16); v += __shfl_down(v, 8);
                v += __shfl_down(v, 4);  v += __shfl_down(v, 2);  v += __shfl_down(v, 1);
                if (lane == 0) out_ds[b * 400 + (l0 + l) * 8 + d] = v;
            }
        }
    }
}

// ---------------------------------------------------------------------------
extern "C" void kernel_launch(void* const* d_in, const int* in_sizes, int n_in,
                              void* d_out, int out_size, void* d_ws, size_t ws_size,
                              hipStream_t stream)
{
    const int*   input     = (const int*)d_in[0];
    const int*   cand      = (const int*)d_in[1];
    const float* emb_table = (const float*)d_in[4];
    const float* Wd        = (const float*)d_in[5];
    const float* Wk        = (const float*)d_in[6];
    const float* bk        = (const float*)d_in[7];
    const float* W1        = (const float*)d_in[8];
    const float* b1        = (const float*)d_in[9];
    const float* w_score   = (const float*)d_in[10];
    const float* Wc        = (const float*)d_in[11];
    const float* bc        = (const float*)d_in[12];

    float* out = (float*)d_out;
    float* out_cat  = out + OFF_CAT;
    float* out_ds   = out + OFF_DS;
    float* out_dsc  = out + OFF_DSC;
    float* out_emb  = out + OFF_EMB;
    float* out_embc = out + OFF_EMBC;
    float* out_loss = out + OFF_LOSS;

    float* ws       = (float*)d_ws;
    float* ws_spart = ws + WS_SPART;
    float* ws_pk    = ws + WS_PK;
    float* ws_pkcT  = ws + WS_PKCT;
    float* ws_wp    = ws + WS_WP;
    float* ws_bp    = ws + WS_BP;

    k_prep<<<65, 128, 0, stream>>>(Wk, bk, W1, ws_wp, ws_bp, out_loss);
    k_main<<<1252, 256, 0, stream>>>(input, cand, emb_table, Wd, ws_wp, ws_bp,
                                     out_emb, out_embc, ws_pk, ws_pkcT, ws_spart);
    k_tail<<<656, 256, 0, stream>>>(ws_spart, ws_pk, ws_pkcT, W1, b1, w_score,
                                    Wc, bc, out_cat, out_ds, out_dsc, out_loss);
}